// Round 1
// baseline (357.132 us; speedup 1.0000x reference)
//
#include <hip/hip_runtime.h>

// DifferentiableTMO: per-batch piecewise-linear CRF LUT over 8x3x1080x1920 fp32.
// HBM floor: 199MB read + 199MB write ~= 63us @6.3TB/s.
// R3: single-level LUT. Direct per-bin (slope,intercept) table (exact for the
//     ~87.5% of bins with no breakpoint); sentinel slope + packed j|count for
//     mixed bins -> rare fallback walk. Common path: 1 ds_read_b64 + fma
//     (was: ds_read_u16 -> dependent while -> ds_read_b64).
//     M=2048 keeps LDS at ~19.5KB so 8 blocks/CU (full 32-wave) residency.

#define KS 256          // CRF sample points
#define NB 25           // PCA basis curves
#define M_BINS 2048     // bucket bins over [0,1)
#define BINS_PER_THR (M_BINS / 256)   // 8
#define NPIX_PER_B 6220800            // 3*1080*1920
#define NP4 (NPIX_PER_B / 4)          // 1555200 float4 per batch

#define SENTINEL 0xFFFFFFFFu          // negative NaN; real slopes are finite
                                      // (E strictly increasing => no 0/0)

typedef float nvec4 __attribute__((ext_vector_type(4)));   // native vector for nt-store

__device__ __forceinline__ void nt_store4(float4* dst, float4 v)
{
    __builtin_nontemporal_store(*(const nvec4*)&v, (nvec4*)dst);
}

__device__ __forceinline__ float interp_one(float x,
                                            const float* __restrict__ sE,
                                            const float2* __restrict__ sSeg,
                                            const float2* __restrict__ sBin)
{
    // x in [0,1): m = floor(x*2048) exact (x*2^11 is an exponent shift)
    int m = (int)(x * (float)M_BINS);
    m = (m > M_BINS - 1) ? (M_BINS - 1) : m;
    float2 sg = sBin[m];               // single ds_read_b64 on the common path
    if (__builtin_expect(__float_as_uint(sg.x) == SENTINEL, 0)) {
        // mixed bin: decode start index + breakpoint count, short walk
        unsigned int pk = __float_as_uint(sg.y);
        unsigned int j  = pk & 0x1FFu;     // upper_bound(E, bin_start)
        unsigned int c  = pk >> 9;         // breakpoints inside this bin
        while (c) {
            if (sE[j] > x) break;
            ++j; --c;
        }
        sg = sSeg[j];
    }
    float y = fmaf(sg.x, x, sg.y);
    return fminf(fmaxf(y, 0.0f), 1.0f);
}

__global__ __launch_bounds__(256, 8)
void tmo_lut_kernel(const float* __restrict__ hdr,
                    const float* __restrict__ w,
                    const float* __restrict__ E,
                    const float* __restrict__ f0,
                    const float* __restrict__ Hb,
                    float* __restrict__ out)
{
    __shared__ float  sE[KS];                     // 1 KB
    __shared__ float2 sSeg[KS + 1];               // 2056 B: (slope,intercept) by upper_bound idx
    __shared__ float2 sBin[M_BINS];               // 16 KB: per-bin direct segment / sentinel

    // sC (per-batch curve values) is only live during setup -> overlay on sBin
    float* sC = (float*)sBin;                     // 256 floats = first 1 KB of sBin

    const int tid = threadIdx.x;
    const int b   = blockIdx.y;

    // ---- stage E, per-batch curve: curve[k] = f0[k] + sum_n Hb[k,n]*w[b,n] ----
    sE[tid] = E[tid];
    {
        float acc = f0[tid];
        const float* wb = w + b * NB;   // block-uniform -> scalar loads
        const float* hb = Hb + tid * NB;
        #pragma unroll
        for (int n = 0; n < NB; ++n) acc = fmaf(hb[n], wb[n], acc);
        sC[tid] = acc;
    }
    __syncthreads();

    // ---- segment table: for j = upper_bound(E,x), y = slope*x + intercept ----
    if (tid == 0) {
        sSeg[0]  = make_float2(0.0f, sC[0]);       // x < E[0]    -> curve[0]
        sSeg[KS] = make_float2(0.0f, sC[KS - 1]);  // x >= E[K-1] -> curve[K-1]
    } else {
        float e0 = sE[tid - 1], e1 = sE[tid];
        float c0 = sC[tid - 1], c1 = sC[tid];
        float sl = (c1 - c0) / (e1 - e0);
        float bi = fmaf(-sl, e0, c0);              // intercept = c0 - sl*e0
        sSeg[tid] = make_float2(sl, bi);
    }
    __syncthreads();                               // sC dead after this point

    // ---- direct bin table: pure bin -> its segment; mixed bin -> sentinel+packed ----
    {
        const float h = 1.0f / (float)M_BINS;      // m*h exact for m < 2^11
        int m0 = tid * BINS_PER_THR;
        float v0 = (float)m0 * h;
        int lo = 0, hi = KS;
        while (lo < hi) {                          // binary search: first E > v0
            int mid = (lo + hi) >> 1;
            if (sE[mid] <= v0) lo = mid + 1; else hi = mid;
        }
        int j = lo;
        #pragma unroll
        for (int t = 0; t < BINS_PER_THR; ++t) {
            int m = m0 + t;
            float vn = (float)(m + 1) * h;
            int jn = j;
            while (jn < KS && sE[jn] <= vn) ++jn;  // first E > (m+1)/M
            int c = jn - j;                        // breakpoints in bin
            float2 e;
            if (c == 0) {
                e = sSeg[j];                       // whole bin on one segment
            } else {
                e.x = __uint_as_float(SENTINEL);
                e.y = __uint_as_float((unsigned)j | ((unsigned)c << 9));
            }
            sBin[m] = e;                           // overwrites sC region (dead)
            j = jn;
        }
    }
    __syncthreads();

    // ---- streaming loop: one batch per blockIdx.y, float4 in/out, U=4 MLP ----
    const float4* __restrict__ in4 = (const float4*)(hdr + (size_t)b * NPIX_PER_B);
    float4*                   out4 = (float4*)(out + (size_t)b * NPIX_PER_B);

    const int stride = gridDim.x * blockDim.x;     // 65536
    int i = blockIdx.x * blockDim.x + tid;

    for (; i + 3 * stride < NP4; i += 4 * stride) {
        float4 p0 = in4[i];
        float4 p1 = in4[i +     stride];
        float4 p2 = in4[i + 2 * stride];
        float4 p3 = in4[i + 3 * stride];
        float4 r;
        r.x = interp_one(p0.x, sE, sSeg, sBin);
        r.y = interp_one(p0.y, sE, sSeg, sBin);
        r.z = interp_one(p0.z, sE, sSeg, sBin);
        r.w = interp_one(p0.w, sE, sSeg, sBin);
        nt_store4(&out4[i], r);
        r.x = interp_one(p1.x, sE, sSeg, sBin);
        r.y = interp_one(p1.y, sE, sSeg, sBin);
        r.z = interp_one(p1.z, sE, sSeg, sBin);
        r.w = interp_one(p1.w, sE, sSeg, sBin);
        nt_store4(&out4[i + stride], r);
        r.x = interp_one(p2.x, sE, sSeg, sBin);
        r.y = interp_one(p2.y, sE, sSeg, sBin);
        r.z = interp_one(p2.z, sE, sSeg, sBin);
        r.w = interp_one(p2.w, sE, sSeg, sBin);
        nt_store4(&out4[i + 2 * stride], r);
        r.x = interp_one(p3.x, sE, sSeg, sBin);
        r.y = interp_one(p3.y, sE, sSeg, sBin);
        r.z = interp_one(p3.z, sE, sSeg, sBin);
        r.w = interp_one(p3.w, sE, sSeg, sBin);
        nt_store4(&out4[i + 3 * stride], r);
    }
    for (; i < NP4; i += stride) {
        float4 p = in4[i];
        float4 r;
        r.x = interp_one(p.x, sE, sSeg, sBin);
        r.y = interp_one(p.y, sE, sSeg, sBin);
        r.z = interp_one(p.z, sE, sSeg, sBin);
        r.w = interp_one(p.w, sE, sSeg, sBin);
        nt_store4(&out4[i], r);
    }
}

extern "C" void kernel_launch(void* const* d_in, const int* in_sizes, int n_in,
                              void* d_out, int out_size, void* d_ws, size_t ws_size,
                              hipStream_t stream)
{
    const float* hdr = (const float*)d_in[0];  // [8,3,1080,1920]
    const float* w   = (const float*)d_in[1];  // [8,25]
    const float* E   = (const float*)d_in[2];  // [256] sorted
    const float* f0  = (const float*)d_in[3];  // [256]
    const float* Hb  = (const float*)d_in[4];  // [256,25]
    float* out = (float*)d_out;

    dim3 grid(256, 8, 1);   // 2048 blocks = 8 blocks/CU on 256 CUs, 32 waves/CU
    dim3 block(256, 1, 1);
    tmo_lut_kernel<<<grid, block, 0, stream>>>(hdr, w, E, f0, Hb, out);
}